// Round 4
// baseline (109.950 us; speedup 1.0000x reference)
//
#include <hip/hip_runtime.h>
#include <hip/hip_bf16.h>

typedef __attribute__((ext_vector_type(8))) short bf16x8;
typedef __attribute__((ext_vector_type(16))) float f32x16;

__device__ __forceinline__ unsigned short f2b(float f) {
  __hip_bfloat16 h = __float2bfloat16(f);
  unsigned short u; __builtin_memcpy(&u, &h, sizeof(u));
  return u;
}
__device__ __forceinline__ unsigned int pk2(float lo, float hi) {
  return (unsigned int)f2b(lo) | ((unsigned int)f2b(hi) << 16);
}

constexpr int S_LEN = 2048;
constexpr int DIM   = 64;
constexpr int QB    = 64;   // q rows per block
constexpr int KB    = 64;   // kv rows per iteration per pair
constexpr int NPAIR = 4;    // wave-pairs splitting the KV range
constexpr int ITERS = S_LEN / KB / NPAIR;  // 8
constexpr float SC_LOG2E = 0.125f * 1.44269504088896f;
constexpr float THR_RAW  = 8.0f / SC_LOG2E;   // defer-max threshold (raw score units)

__device__ __forceinline__ void load_tile(float4 (&dst)[8], const float* src, int tp) {
  #pragma unroll
  for (int sb = 0; sb < 2; ++sb) {
    int s = tp + sb * 128;
    int rowg = s >> 4, colg = s & 15;
    const float* p = src + 4 * rowg * DIM + 4 * colg;
    #pragma unroll
    for (int i = 0; i < 4; ++i)
      dst[sb * 4 + i] = *reinterpret_cast<const float4*>(p + i * DIM);
  }
}

__device__ __forceinline__ float fcomp(const float4& v, int i) {
  return i == 0 ? v.x : i == 1 ? v.y : i == 2 ? v.z : v.w;
}

// K: row k, 128B rows, 16B-granule XOR swizzle key (k&7)<<4  -> QK reads conflict-free
// V^T: row d, 128B rows, key (d&7)<<4                        -> PV reads conflict-free
__device__ __forceinline__ void store_tile(const float4 (&pre)[8],
                                           unsigned char* Kb, unsigned char* Vb, int tp) {
  #pragma unroll
  for (int sb = 0; sb < 2; ++sb) {
    int s = tp + sb * 128;
    int rowg = s >> 4, colg = s & 15;
    #pragma unroll
    for (int i = 0; i < 4; ++i) {          // K rows: d-contiguous pairs
      const float4& vv = pre[sb * 4 + i];
      int row = 4 * rowg + i;
      uint2 w; w.x = pk2(vv.x, vv.y); w.y = pk2(vv.z, vv.w);
      *reinterpret_cast<uint2*>(Kb + row * 128 + ((8 * colg) ^ ((row & 7) << 4))) = w;
    }
    #pragma unroll
    for (int i = 0; i < 4; ++i) {          // V^T rows: k-contiguous pairs
      int d = 4 * colg + i;
      uint2 w;
      w.x = pk2(fcomp(pre[sb * 4 + 0], i), fcomp(pre[sb * 4 + 1], i));
      w.y = pk2(fcomp(pre[sb * 4 + 2], i), fcomp(pre[sb * 4 + 3], i));
      *reinterpret_cast<uint2*>(Vb + d * 128 + ((8 * rowg) ^ ((d & 7) << 4))) = w;
    }
  }
}

__device__ __forceinline__ void compute_tile(const unsigned char* Kb, const unsigned char* Vb,
                                             const bf16x8 (&qf)[4], f32x16 (&oacc)[2],
                                             float& m_run, float& lsum,
                                             int r, int hi, int kkey) {
  // S^T = K * Q^T
  f32x16 st[2];
  __builtin_amdgcn_s_setprio(1);
  #pragma unroll
  for (int kt = 0; kt < 2; ++kt) {
    f32x16 acc;
    #pragma unroll
    for (int i = 0; i < 16; ++i) acc[i] = 0.f;
    #pragma unroll
    for (int c = 0; c < 4; ++c) {
      bf16x8 a = *reinterpret_cast<const bf16x8*>(
          Kb + (kt * 32 + r) * 128 + ((32 * c + 16 * hi) ^ kkey));
      acc = __builtin_amdgcn_mfma_f32_32x32x16_bf16(a, qf[c], acc, 0, 0, 0);
    }
    st[kt] = acc;
  }
  __builtin_amdgcn_s_setprio(0);

  // online softmax with defer-max (T13)
  float mx = st[0][0];
  #pragma unroll
  for (int i = 1; i < 16; ++i) mx = fmaxf(mx, st[0][i]);
  #pragma unroll
  for (int i = 0; i < 16; ++i) mx = fmaxf(mx, st[1][i]);
  mx = fmaxf(mx, __shfl_xor(mx, 32));
  if (!__all(mx <= m_run + THR_RAW)) {
    float mnew  = fmaxf(m_run, mx);
    float alpha = exp2f((m_run - mnew) * SC_LOG2E);
    m_run = mnew;
    lsum *= alpha;
    #pragma unroll
    for (int i = 0; i < 16; ++i) { oacc[0][i] *= alpha; oacc[1][i] *= alpha; }
  }
  float mc = m_run * SC_LOG2E;
  float psum = 0.f;
  #pragma unroll
  for (int kt = 0; kt < 2; ++kt) {
    #pragma unroll
    for (int i = 0; i < 16; ++i) {
      float e = exp2f(fmaf(st[kt][i], SC_LOG2E, -mc));
      st[kt][i] = e;
      psum += e;
    }
  }
  psum += __shfl_xor(psum, 32);
  lsum += psum;

  // P^T -> bf16 frags in-register, O^T += V^T * P^T
  #pragma unroll
  for (int kt = 0; kt < 2; ++kt) {
    unsigned int own[8], cross[8];
    #pragma unroll
    for (int a = 0; a < 4; ++a) {
      own[a * 2 + 0] = pk2(st[kt][4 * a + 0], st[kt][4 * a + 1]);
      own[a * 2 + 1] = pk2(st[kt][4 * a + 2], st[kt][4 * a + 3]);
    }
    #pragma unroll
    for (int e = 0; e < 8; ++e) cross[e] = __shfl_xor(own[e], 32);
    __builtin_amdgcn_s_setprio(1);
    #pragma unroll
    for (int kc = 0; kc < 2; ++kc) {
      union { unsigned int u[4]; bf16x8 v; } pf;
      pf.u[0] = hi ? cross[4 * kc + 2] : own[4 * kc + 0];
      pf.u[1] = hi ? cross[4 * kc + 3] : own[4 * kc + 1];
      pf.u[2] = hi ? own[4 * kc + 2]   : cross[4 * kc + 0];
      pf.u[3] = hi ? own[4 * kc + 3]   : cross[4 * kc + 1];
      #pragma unroll
      for (int dt = 0; dt < 2; ++dt) {
        bf16x8 vf = *reinterpret_cast<const bf16x8*>(
            Vb + (dt * 32 + r) * 128 + ((64 * kt + 32 * kc + 16 * hi) ^ kkey));
        oacc[dt] = __builtin_amdgcn_mfma_f32_32x32x16_bf16(vf, pf.v, oacc[dt], 0, 0, 0);
      }
    }
    __builtin_amdgcn_s_setprio(0);
  }
}

__global__ __launch_bounds__(512, 4)
void attn_fwd(const float* __restrict__ x1, const float* __restrict__ x2,
              float* __restrict__ out) {
  __shared__ __align__(16) unsigned char smem[67584];  // staging 64KB; combine [4][64][66] f32
  __shared__ float mlbuf[NPAIR][2][QB];

  // T1: bijective XCD swizzle (512 = 8 XCD * 64): one batch's 32 blocks -> one XCD
  const int logical = (blockIdx.x & 7) * 64 + (blockIdx.x >> 3);
  const int b    = logical >> 5;
  const int q0   = (logical & 31) * QB;
  const int tid  = threadIdx.x;
  const int wave = tid >> 6;
  const int pair = wave >> 1;
  const int wid  = wave & 1;
  const int lane = tid & 63;
  const int r    = lane & 31;
  const int hi   = lane >> 5;
  const int tp   = tid & 127;
  const int kkey = (r & 7) << 4;

  unsigned char* Kb = smem + pair * 16384;
  unsigned char* Vb = Kb + 8192;

  const float* Qp     = x1 + ((size_t)b * S_LEN + q0 + wid * 32 + r) * DIM;
  const float* KVbase = x2 + ((size_t)b * S_LEN + (size_t)pair * ITERS * KB) * DIM;

  // Q as B-operand: qf[c][j] = Q[q=r][16c + 8hi + j]
  bf16x8 qf[4];
  #pragma unroll
  for (int c = 0; c < 4; ++c) {
    const float* p = Qp + 16 * c + 8 * hi;
    bf16x8 v;
    #pragma unroll
    for (int j = 0; j < 8; ++j) v[j] = (short)f2b(p[j]);
    qf[c] = v;
  }

  f32x16 oacc[2];
  #pragma unroll
  for (int i = 0; i < 16; ++i) { oacc[0][i] = 0.f; oacc[1][i] = 0.f; }
  float m_run = -3.0e38f;
  float lsum  = 0.f;

  float4 A[8], B[8];
  load_tile(A, KVbase, tp);
  #pragma unroll 1
  for (int t = 0; t < ITERS; t += 2) {
    __syncthreads();
    load_tile(B, KVbase + (size_t)(t + 1) * KB * DIM, tp);   // prefetch t+1
    store_tile(A, Kb, Vb, tp);                               // write tile t
    __syncthreads();
    compute_tile(Kb, Vb, qf, oacc, m_run, lsum, r, hi, kkey);

    __syncthreads();
    if (t + 2 < ITERS) load_tile(A, KVbase + (size_t)(t + 2) * KB * DIM, tp);
    store_tile(B, Kb, Vb, tp);                               // write tile t+1
    __syncthreads();
    compute_tile(Kb, Vb, qf, oacc, m_run, lsum, r, hi, kkey);
  }

  // ---- combine the 4 pairs' partials (reuse staging LDS, fp32)
  __syncthreads();
  if (hi == 0) {
    mlbuf[pair][0][wid * 32 + r] = m_run;
    mlbuf[pair][1][wid * 32 + r] = lsum;
  }
  float* Ocomb = reinterpret_cast<float*>(smem);  // [4][64][66]
  #pragma unroll
  for (int dt = 0; dt < 2; ++dt) {
    #pragma unroll
    for (int i = 0; i < 16; ++i) {
      int d = dt * 32 + (i & 3) + 8 * (i >> 2) + 4 * hi;
      Ocomb[(pair * QB + wid * 32 + r) * 66 + d] = oacc[dt][i];
    }
  }
  __syncthreads();

  int q  = tid >> 3;
  int dg = tid & 7;
  float m0 = mlbuf[0][0][q], m1 = mlbuf[1][0][q], m2 = mlbuf[2][0][q], m3 = mlbuf[3][0][q];
  float l0 = mlbuf[0][1][q], l1 = mlbuf[1][1][q], l2 = mlbuf[2][1][q], l3 = mlbuf[3][1][q];
  float ms = fmaxf(fmaxf(m0, m1), fmaxf(m2, m3));
  float w0 = exp2f((m0 - ms) * SC_LOG2E);
  float w1 = exp2f((m1 - ms) * SC_LOG2E);
  float w2 = exp2f((m2 - ms) * SC_LOG2E);
  float w3 = exp2f((m3 - ms) * SC_LOG2E);
  float inv = 1.0f / (l0 * w0 + l1 * w1 + l2 * w2 + l3 * w3);
  float o[8];
  #pragma unroll
  for (int j = 0; j < 8; ++j) {
    o[j] = (Ocomb[(0 * QB + q) * 66 + dg * 8 + j] * w0 +
            Ocomb[(1 * QB + q) * 66 + dg * 8 + j] * w1 +
            Ocomb[(2 * QB + q) * 66 + dg * 8 + j] * w2 +
            Ocomb[(3 * QB + q) * 66 + dg * 8 + j] * w3) * inv;
  }
  float* outp = out + ((size_t)b * S_LEN + q0 + q) * DIM + dg * 8;
  float4 s0; s0.x = o[0]; s0.y = o[1]; s0.z = o[2]; s0.w = o[3];
  float4 s1; s1.x = o[4]; s1.y = o[5]; s1.z = o[6]; s1.w = o[7];
  *reinterpret_cast<float4*>(outp + 0) = s0;
  *reinterpret_cast<float4*>(outp + 4) = s1;
}

extern "C" void kernel_launch(void* const* d_in, const int* in_sizes, int n_in,
                              void* d_out, int out_size, void* d_ws, size_t ws_size,
                              hipStream_t stream) {
  const float* x1 = (const float*)d_in[0];
  const float* x2 = (const float*)d_in[1];
  float* outp = (float*)d_out;
  dim3 grid(16 * (S_LEN / QB));  // 512 blocks, 512 threads (8 waves)
  attn_fwd<<<grid, 512, 0, stream>>>(x1, x2, outp);
}

// Round 5
// 89.532 us; speedup vs baseline: 1.2280x; 1.2280x over previous
//
#include <hip/hip_runtime.h>
#include <hip/hip_bf16.h>

typedef __attribute__((ext_vector_type(8))) short bf16x8;
typedef __attribute__((ext_vector_type(16))) float f32x16;

__device__ __forceinline__ unsigned short f2b(float f) {
  __hip_bfloat16 h = __float2bfloat16(f);
  unsigned short u; __builtin_memcpy(&u, &h, sizeof(u));
  return u;
}
__device__ __forceinline__ unsigned int pk2(float lo, float hi) {
  return (unsigned int)f2b(lo) | ((unsigned int)f2b(hi) << 16);
}

constexpr int S_LEN = 2048;
constexpr int DIM   = 64;
constexpr int QB    = 64;
constexpr int KB    = 64;
constexpr int NPAIR = 4;
constexpr int ITERS = S_LEN / KB / NPAIR;  // 8
constexpr float SC_LOG2E = 0.125f * 1.44269504088896f;
constexpr float THR_RAW  = 8.0f / SC_LOG2E;

__device__ __forceinline__ void load_tile(float4 (&dst)[8], const float* src, int tp) {
  #pragma unroll
  for (int sb = 0; sb < 2; ++sb) {
    int s = tp + sb * 128;
    int rowg = s >> 4, colg = s & 15;
    const float* p = src + 4 * rowg * DIM + 4 * colg;
    #pragma unroll
    for (int i = 0; i < 4; ++i)
      dst[sb * 4 + i] = *reinterpret_cast<const float4*>(p + i * DIM);
  }
}

__device__ __forceinline__ float fcomp(const float4& v, int i) {
  return i == 0 ? v.x : i == 1 ? v.y : i == 2 ? v.z : v.w;
}

// K: row k (128B), elem d at byte (2d)^((k&7)<<4)      -> writes 4/bank, reads 8/bank (min)
// V^T: row d (128B), elem k at byte (2k)^(((d>>2)&7)<<4) -> writes 4/bank, reads 8/bank (min)
__device__ __forceinline__ void store_tile(const float4 (&pre)[8],
                                           unsigned char* Kb, unsigned char* Vb, int tp) {
  #pragma unroll
  for (int sb = 0; sb < 2; ++sb) {
    int s = tp + sb * 128;
    int rowg = s >> 4, colg = s & 15;
    #pragma unroll
    for (int i = 0; i < 4; ++i) {          // K rows: d-contiguous pairs
      const float4& vv = pre[sb * 4 + i];
      int row = 4 * rowg + i;
      uint2 w; w.x = pk2(vv.x, vv.y); w.y = pk2(vv.z, vv.w);
      *reinterpret_cast<uint2*>(Kb + row * 128 + ((8 * colg) ^ ((row & 7) << 4))) = w;
    }
    int vkeyw = (colg & 7) << 4;           // = ((d>>2)&7)<<4 since d = 4*colg+i
    #pragma unroll
    for (int i = 0; i < 4; ++i) {          // V^T rows: k-contiguous pairs
      int d = 4 * colg + i;
      uint2 w;
      w.x = pk2(fcomp(pre[sb * 4 + 0], i), fcomp(pre[sb * 4 + 1], i));
      w.y = pk2(fcomp(pre[sb * 4 + 2], i), fcomp(pre[sb * 4 + 3], i));
      *reinterpret_cast<uint2*>(Vb + d * 128 + ((8 * rowg) ^ vkeyw)) = w;
    }
  }
}

__device__ __forceinline__ void compute_tile(const unsigned char* Kb, const unsigned char* Vb,
                                             const bf16x8 (&qf)[4], f32x16 (&oacc)[2],
                                             float& m_run, float& lsum,
                                             int r, int hi, int kkey, int vkey) {
  // S^T = K * Q^T
  f32x16 st[2];
  __builtin_amdgcn_s_setprio(1);
  #pragma unroll
  for (int kt = 0; kt < 2; ++kt) {
    f32x16 acc;
    #pragma unroll
    for (int i = 0; i < 16; ++i) acc[i] = 0.f;
    #pragma unroll
    for (int c = 0; c < 4; ++c) {
      bf16x8 a = *reinterpret_cast<const bf16x8*>(
          Kb + (kt * 32 + r) * 128 + ((32 * c + 16 * hi) ^ kkey));
      acc = __builtin_amdgcn_mfma_f32_32x32x16_bf16(a, qf[c], acc, 0, 0, 0);
    }
    st[kt] = acc;
  }
  __builtin_amdgcn_s_setprio(0);

  // online softmax, tree max (depth 5), defer-max (T13)
  float mt[16];
  #pragma unroll
  for (int i = 0; i < 16; ++i) mt[i] = fmaxf(st[0][i], st[1][i]);
  #pragma unroll
  for (int sfs = 8; sfs > 0; sfs >>= 1)
    #pragma unroll
    for (int i = 0; i < sfs; ++i) mt[i] = fmaxf(mt[i], mt[i + sfs]);
  float mx = fmaxf(mt[0], __shfl_xor(mt[0], 32));
  if (!__all(mx <= m_run + THR_RAW)) {
    float mnew  = fmaxf(m_run, mx);
    float alpha = exp2f((m_run - mnew) * SC_LOG2E);
    m_run = mnew;
    lsum *= alpha;
    #pragma unroll
    for (int i = 0; i < 16; ++i) { oacc[0][i] *= alpha; oacc[1][i] *= alpha; }
  }
  float mc = m_run * SC_LOG2E;
  float pt[16];
  #pragma unroll
  for (int kt = 0; kt < 2; ++kt)
    #pragma unroll
    for (int i = 0; i < 16; ++i)
      st[kt][i] = exp2f(fmaf(st[kt][i], SC_LOG2E, -mc));
  #pragma unroll
  for (int i = 0; i < 16; ++i) pt[i] = st[0][i] + st[1][i];
  #pragma unroll
  for (int sfs = 8; sfs > 0; sfs >>= 1)
    #pragma unroll
    for (int i = 0; i < sfs; ++i) pt[i] += pt[i + sfs];
  lsum += pt[0] + __shfl_xor(pt[0], 32);

  // P^T -> bf16 frags in-register, O^T += V^T * P^T
  #pragma unroll
  for (int kt = 0; kt < 2; ++kt) {
    unsigned int own[8], cross[8];
    #pragma unroll
    for (int a = 0; a < 4; ++a) {
      own[a * 2 + 0] = pk2(st[kt][4 * a + 0], st[kt][4 * a + 1]);
      own[a * 2 + 1] = pk2(st[kt][4 * a + 2], st[kt][4 * a + 3]);
    }
    #pragma unroll
    for (int e = 0; e < 8; ++e) cross[e] = __shfl_xor(own[e], 32);
    __builtin_amdgcn_s_setprio(1);
    #pragma unroll
    for (int kc = 0; kc < 2; ++kc) {
      union { unsigned int u[4]; bf16x8 v; } pf;
      pf.u[0] = hi ? cross[4 * kc + 2] : own[4 * kc + 0];
      pf.u[1] = hi ? cross[4 * kc + 3] : own[4 * kc + 1];
      pf.u[2] = hi ? own[4 * kc + 2]   : cross[4 * kc + 0];
      pf.u[3] = hi ? own[4 * kc + 3]   : cross[4 * kc + 1];
      #pragma unroll
      for (int dt = 0; dt < 2; ++dt) {
        bf16x8 vf = *reinterpret_cast<const bf16x8*>(
            Vb + (dt * 32 + r) * 128 + ((64 * kt + 32 * kc + 16 * hi) ^ vkey));
        oacc[dt] = __builtin_amdgcn_mfma_f32_32x32x16_bf16(vf, pf.v, oacc[dt], 0, 0, 0);
      }
    }
    __builtin_amdgcn_s_setprio(0);
  }
}

__global__ __launch_bounds__(512, 4)
void attn_fwd(const float* __restrict__ x1, const float* __restrict__ x2,
              float* __restrict__ out) {
  __shared__ __align__(16) unsigned char smem[67584];  // staging 64KB; combine [4][64][66] f32
  __shared__ float mlbuf[NPAIR][2][QB];

  // T1: bijective XCD swizzle (512 = 8 XCD * 64): one batch's 32 blocks -> one XCD
  const int logical = (blockIdx.x & 7) * 64 + (blockIdx.x >> 3);
  const int b    = logical >> 5;
  const int q0   = (logical & 31) * QB;
  const int tid  = threadIdx.x;
  const int wave = tid >> 6;
  const int pair = wave >> 1;
  const int wid  = wave & 1;
  const int lane = tid & 63;
  const int r    = lane & 31;
  const int hi   = lane >> 5;
  const int tp   = tid & 127;
  const int kkey = (r & 7) << 4;
  const int vkey = ((r >> 2) & 7) << 4;

  unsigned char* Kb = smem + pair * 16384;
  unsigned char* Vb = Kb + 8192;

  const float* Qp     = x1 + ((size_t)b * S_LEN + q0 + wid * 32 + r) * DIM;
  const float* KVbase = x2 + ((size_t)b * S_LEN + (size_t)pair * ITERS * KB) * DIM;

  bf16x8 qf[4];
  #pragma unroll
  for (int c = 0; c < 4; ++c) {
    const float* p = Qp + 16 * c + 8 * hi;
    bf16x8 v;
    #pragma unroll
    for (int j = 0; j < 8; ++j) v[j] = (short)f2b(p[j]);
    qf[c] = v;
  }

  f32x16 oacc[2];
  #pragma unroll
  for (int i = 0; i < 16; ++i) { oacc[0][i] = 0.f; oacc[1][i] = 0.f; }
  float m_run = -3.0e38f;
  float lsum  = 0.f;

  float4 A[8];
  load_tile(A, KVbase, tp);
  #pragma unroll 1
  for (int t = 0; t < ITERS; ++t) {
    __syncthreads();
    store_tile(A, Kb, Vb, tp);                 // consumes A (vmcnt waited by compiler)
    __builtin_amdgcn_sched_barrier(0);         // pin: next loads must NOT hoist above (reg reuse)
    int tn = (t + 1 < ITERS) ? t + 1 : t;      // clamp: no OOB, straight-line
    load_tile(A, KVbase + (size_t)tn * KB * DIM, tp);   // T14: in flight during compute
    __syncthreads();
    compute_tile(Kb, Vb, qf, oacc, m_run, lsum, r, hi, kkey, vkey);
  }

  // ---- combine the 4 pairs' partials (reuse staging LDS, fp32)
  __syncthreads();
  if (hi == 0) {
    mlbuf[pair][0][wid * 32 + r] = m_run;
    mlbuf[pair][1][wid * 32 + r] = lsum;
  }
  float* Ocomb = reinterpret_cast<float*>(smem);  // [4][64][66]
  #pragma unroll
  for (int dt = 0; dt < 2; ++dt) {
    #pragma unroll
    for (int i = 0; i < 16; ++i) {
      int d = dt * 32 + (i & 3) + 8 * (i >> 2) + 4 * hi;
      Ocomb[(pair * QB + wid * 32 + r) * 66 + d] = oacc[dt][i];
    }
  }
  __syncthreads();

  int q  = tid >> 3;
  int dg = tid & 7;
  float m0 = mlbuf[0][0][q], m1 = mlbuf[1][0][q], m2 = mlbuf[2][0][q], m3 = mlbuf[3][0][q];
  float l0 = mlbuf[0][1][q], l1 = mlbuf[1][1][q], l2 = mlbuf[2][1][q], l3 = mlbuf[3][1][q];
  float ms = fmaxf(fmaxf(m0, m1), fmaxf(m2, m3));
  float w0 = exp2f((m0 - ms) * SC_LOG2E);
  float w1 = exp2f((m1 - ms) * SC_LOG2E);
  float w2 = exp2f((m2 - ms) * SC_LOG2E);
  float w3 = exp2f((m3 - ms) * SC_LOG2E);
  float inv = 1.0f / (l0 * w0 + l1 * w1 + l2 * w2 + l3 * w3);
  float o[8];
  #pragma unroll
  for (int j = 0; j < 8; ++j) {
    o[j] = (Ocomb[(0 * QB + q) * 66 + dg * 8 + j] * w0 +
            Ocomb[(1 * QB + q) * 66 + dg * 8 + j] * w1 +
            Ocomb[(2 * QB + q) * 66 + dg * 8 + j] * w2 +
            Ocomb[(3 * QB + q) * 66 + dg * 8 + j] * w3) * inv;
  }
  float* outp = out + ((size_t)b * S_LEN + q0 + q) * DIM + dg * 8;
  float4 s0; s0.x = o[0]; s0.y = o[1]; s0.z = o[2]; s0.w = o[3];
  float4 s1; s1.x = o[4]; s1.y = o[5]; s1.z = o[6]; s1.w = o[7];
  *reinterpret_cast<float4*>(outp + 0) = s0;
  *reinterpret_cast<float4*>(outp + 4) = s1;
}

extern "C" void kernel_launch(void* const* d_in, const int* in_sizes, int n_in,
                              void* d_out, int out_size, void* d_ws, size_t ws_size,
                              hipStream_t stream) {
  const float* x1 = (const float*)d_in[0];
  const float* x2 = (const float*)d_in[1];
  float* outp = (float*)d_out;
  dim3 grid(16 * (S_LEN / QB));  // 512 blocks, 512 threads (8 waves)
  attn_fwd<<<grid, 512, 0, stream>>>(x1, x2, outp);
}

// Round 6
// 53.669 us; speedup vs baseline: 2.0487x; 1.6682x over previous
//
#include <hip/hip_runtime.h>
#include <hip/hip_bf16.h>

typedef __attribute__((ext_vector_type(8))) short bf16x8;
typedef __attribute__((ext_vector_type(16))) float f32x16;
typedef __attribute__((address_space(1))) const void gvoid;
typedef __attribute__((address_space(3))) void lvoid;

__device__ __forceinline__ unsigned short f2b(float f) {
  __hip_bfloat16 h = __float2bfloat16(f);
  unsigned short u; __builtin_memcpy(&u, &h, sizeof(u));
  return u;
}
// packed fp32x2 -> bf16x2 (RNE), single instruction
__device__ __forceinline__ unsigned int pk2(float lo, float hi) {
  unsigned int r;
  asm("v_cvt_pk_bf16_f32 %0, %1, %2" : "=v"(r) : "v"(lo), "v"(hi));
  return r;
}
__device__ __forceinline__ float fcomp(const float4& v, int i) {
  return i == 0 ? v.x : i == 1 ? v.y : i == 2 ? v.z : v.w;
}

constexpr int S_LEN = 2048;
constexpr int DIM   = 64;
constexpr int QB    = 64;
constexpr int KB    = 64;
constexpr int NPAIR = 4;
constexpr int ITERS = S_LEN / KB / NPAIR;  // 8
constexpr float SC_LOG2E = 0.125f * 1.44269504088896f;
constexpr float THR_RAW  = 8.0f / SC_LOG2E;

// ---------------- prep: x2 fp32 -> bf16 K-image + V^T-image, pre-swizzled ----------------
// Image per 64-row tile = 16384 B: [0,8192) K rows k: byte(k,d) = k*128 + ((2d)^((k&7)<<4))
//                        [8192,16384) V^T rows d: byte(d,k') = d*128 + ((2k')^(((d>>2)&7)<<4))
__global__ __launch_bounds__(256)
void prep_kv(const float* __restrict__ x2, unsigned char* __restrict__ img) {
  const int blk  = blockIdx.x;          // b*32 + tile (tiles contiguous in memory)
  const int s    = threadIdx.x;
  const int rowg = s >> 4, colg = s & 15;
  const float* src   = x2 + (size_t)blk * 4096;
  unsigned char* dst = img + (size_t)blk * 16384;
  float4 w[4];
  #pragma unroll
  for (int i = 0; i < 4; ++i)
    w[i] = *reinterpret_cast<const float4*>(src + (4 * rowg + i) * DIM + 4 * colg);
  #pragma unroll
  for (int i = 0; i < 4; ++i) {
    int k = 4 * rowg + i;
    uint2 u; u.x = pk2(w[i].x, w[i].y); u.y = pk2(w[i].z, w[i].w);
    *reinterpret_cast<uint2*>(dst + k * 128 + ((8 * colg) ^ ((k & 7) << 4))) = u;
  }
  const int vkeyw = (colg & 7) << 4;    // = ((d>>2)&7)<<4 for d = 4*colg+i
  #pragma unroll
  for (int i = 0; i < 4; ++i) {
    int d = 4 * colg + i;
    uint2 u;
    u.x = pk2(fcomp(w[0], i), fcomp(w[1], i));
    u.y = pk2(fcomp(w[2], i), fcomp(w[3], i));
    *reinterpret_cast<uint2*>(dst + 8192 + d * 128 + ((8 * rowg) ^ vkeyw)) = u;
  }
}

// ---------------- main attention ----------------
__device__ __forceinline__ void compute_tile(const unsigned char* Kb, const unsigned char* Vb,
                                             const bf16x8 (&qf)[4], f32x16 (&oacc)[2],
                                             float& m_run, float& lsum,
                                             int r, int hi, int kkey, int vkey) {
  // S^T = K * Q^T
  f32x16 st[2];
  __builtin_amdgcn_s_setprio(1);
  #pragma unroll
  for (int kt = 0; kt < 2; ++kt) {
    f32x16 acc;
    #pragma unroll
    for (int i = 0; i < 16; ++i) acc[i] = 0.f;
    #pragma unroll
    for (int c = 0; c < 4; ++c) {
      bf16x8 a = *reinterpret_cast<const bf16x8*>(
          Kb + (kt * 32 + r) * 128 + ((32 * c + 16 * hi) ^ kkey));
      acc = __builtin_amdgcn_mfma_f32_32x32x16_bf16(a, qf[c], acc, 0, 0, 0);
    }
    st[kt] = acc;
  }
  __builtin_amdgcn_s_setprio(0);

  // online softmax: tree max, defer-max (T13)
  float mt[16];
  #pragma unroll
  for (int i = 0; i < 16; ++i) mt[i] = fmaxf(st[0][i], st[1][i]);
  #pragma unroll
  for (int sfs = 8; sfs > 0; sfs >>= 1)
    #pragma unroll
    for (int i = 0; i < sfs; ++i) mt[i] = fmaxf(mt[i], mt[i + sfs]);
  float mx = fmaxf(mt[0], __shfl_xor(mt[0], 32));
  if (!__all(mx <= m_run + THR_RAW)) {
    float mnew  = fmaxf(m_run, mx);
    float alpha = exp2f((m_run - mnew) * SC_LOG2E);
    m_run = mnew;
    lsum *= alpha;
    #pragma unroll
    for (int i = 0; i < 16; ++i) { oacc[0][i] *= alpha; oacc[1][i] *= alpha; }
  }
  float mc = m_run * SC_LOG2E;
  float pt[16];
  #pragma unroll
  for (int kt = 0; kt < 2; ++kt)
    #pragma unroll
    for (int i = 0; i < 16; ++i)
      st[kt][i] = exp2f(fmaf(st[kt][i], SC_LOG2E, -mc));
  #pragma unroll
  for (int i = 0; i < 16; ++i) pt[i] = st[0][i] + st[1][i];
  #pragma unroll
  for (int sfs = 8; sfs > 0; sfs >>= 1)
    #pragma unroll
    for (int i = 0; i < sfs; ++i) pt[i] += pt[i + sfs];
  lsum += pt[0] + __shfl_xor(pt[0], 32);

  // P^T -> bf16 frags in-register, O^T += V^T * P^T
  #pragma unroll
  for (int kt = 0; kt < 2; ++kt) {
    unsigned int own[8], cross[8];
    #pragma unroll
    for (int a = 0; a < 4; ++a) {
      own[a * 2 + 0] = pk2(st[kt][4 * a + 0], st[kt][4 * a + 1]);
      own[a * 2 + 1] = pk2(st[kt][4 * a + 2], st[kt][4 * a + 3]);
    }
    #pragma unroll
    for (int e = 0; e < 8; ++e) cross[e] = __shfl_xor(own[e], 32);
    __builtin_amdgcn_s_setprio(1);
    #pragma unroll
    for (int kc = 0; kc < 2; ++kc) {
      union { unsigned int u[4]; bf16x8 v; } pf;
      pf.u[0] = hi ? cross[4 * kc + 2] : own[4 * kc + 0];
      pf.u[1] = hi ? cross[4 * kc + 3] : own[4 * kc + 1];
      pf.u[2] = hi ? own[4 * kc + 2]   : cross[4 * kc + 0];
      pf.u[3] = hi ? own[4 * kc + 3]   : cross[4 * kc + 1];
      #pragma unroll
      for (int dt = 0; dt < 2; ++dt) {
        bf16x8 vf = *reinterpret_cast<const bf16x8*>(
            Vb + (dt * 32 + r) * 128 + ((64 * kt + 32 * kc + 16 * hi) ^ vkey));
        oacc[dt] = __builtin_amdgcn_mfma_f32_32x32x16_bf16(vf, pf.v, oacc[dt], 0, 0, 0);
      }
    }
    __builtin_amdgcn_s_setprio(0);
  }
}

template <bool IMG>
__global__ __launch_bounds__(512, 4)
void attn_fwd(const float* __restrict__ x1, const float* __restrict__ x2,
              const unsigned char* __restrict__ img, float* __restrict__ out) {
  __shared__ __align__(16) unsigned char smem[69632];  // staging 64KB / combine [4][64][67] f32
  __shared__ float mlbuf[NPAIR][2][QB];

  // T1: bijective XCD swizzle (512 = 8 XCD * 64): one batch's 32 blocks -> one XCD
  const int logical = (blockIdx.x & 7) * 64 + (blockIdx.x >> 3);
  const int b    = logical >> 5;
  const int q0   = (logical & 31) * QB;
  const int tid  = threadIdx.x;
  const int wave = tid >> 6;
  const int pair = wave >> 1;
  const int wid  = wave & 1;
  const int lane = tid & 63;
  const int r    = lane & 31;
  const int hi   = lane >> 5;
  const int tp   = tid & 127;
  const int kkey = (r & 7) << 4;
  const int vkey = ((r >> 2) & 7) << 4;

  unsigned char* Kb = smem + pair * 16384;
  unsigned char* Vb = Kb + 8192;

  const float* Qp = x1 + ((size_t)b * S_LEN + q0 + wid * 32 + r) * DIM;

  bf16x8 qf[4];
  #pragma unroll
  for (int c = 0; c < 4; ++c) {
    const float* p = Qp + 16 * c + 8 * hi;
    bf16x8 v;
    #pragma unroll
    for (int j = 0; j < 8; ++j) v[j] = (short)f2b(p[j]);
    qf[c] = v;
  }

  f32x16 oacc[2];
  #pragma unroll
  for (int i = 0; i < 16; ++i) { oacc[0][i] = 0.f; oacc[1][i] = 0.f; }
  float m_run = -3.0e38f;
  float lsum  = 0.f;

  #pragma unroll 1
  for (int t = 0; t < ITERS; ++t) {
    __syncthreads();   // previous compute done, LDS free
    if constexpr (IMG) {
      // 16 KB tile image -> LDS, zero VALU, zero register round-trip
      const unsigned char* gsrc =
          img + ((size_t)(b * 32 + pair * ITERS + t)) * 16384 + wid * 8192 + lane * 16;
      unsigned char* ldst = Kb + wid * 8192;   // wave-uniform; HW adds lane*16
      #pragma unroll
      for (int j = 0; j < 8; ++j)
        __builtin_amdgcn_global_load_lds((gvoid*)(gsrc + j * 1024),
                                         (lvoid*)(ldst + j * 1024), 16, 0, 0);
      asm volatile("s_waitcnt vmcnt(0)" ::: "memory");
    } else {
      // fallback: incremental staging (<=16 floats live, no spill)
      const float* src = x2 + ((size_t)b * S_LEN + (size_t)(pair * ITERS + t) * KB) * DIM;
      #pragma unroll
      for (int sb = 0; sb < 2; ++sb) {
        int s = tp + sb * 128;
        int rowg = s >> 4, colg = s & 15;
        const float* p = src + 4 * rowg * DIM + 4 * colg;
        float4 w0 = *reinterpret_cast<const float4*>(p + 0 * DIM);
        float4 w1 = *reinterpret_cast<const float4*>(p + 1 * DIM);
        float4 w2 = *reinterpret_cast<const float4*>(p + 2 * DIM);
        float4 w3 = *reinterpret_cast<const float4*>(p + 3 * DIM);
        #pragma unroll
        for (int i = 0; i < 4; ++i) {
          int row = 4 * rowg + i;
          float4 wv = i == 0 ? w0 : i == 1 ? w1 : i == 2 ? w2 : w3;
          uint2 u; u.x = pk2(wv.x, wv.y); u.y = pk2(wv.z, wv.w);
          *reinterpret_cast<uint2*>(Kb + row * 128 + ((8 * colg) ^ ((row & 7) << 4))) = u;
        }
        int vkeyw = (colg & 7) << 4;
        #pragma unroll
        for (int i = 0; i < 4; ++i) {
          int d = 4 * colg + i;
          uint2 u;
          u.x = pk2(fcomp(w0, i), fcomp(w1, i));
          u.y = pk2(fcomp(w2, i), fcomp(w3, i));
          *reinterpret_cast<uint2*>(Vb + d * 128 + ((8 * rowg) ^ vkeyw)) = u;
        }
      }
    }
    __syncthreads();
    compute_tile(Kb, Vb, qf, oacc, m_run, lsum, r, hi, kkey, vkey);
  }

  // ---- combine the 4 pairs' partials (reuse staging LDS, fp32, stride 67)
  __syncthreads();
  if (hi == 0) {
    mlbuf[pair][0][wid * 32 + r] = m_run;
    mlbuf[pair][1][wid * 32 + r] = lsum;
  }
  float* Ocomb = reinterpret_cast<float*>(smem);  // [4][64][67]
  #pragma unroll
  for (int dt = 0; dt < 2; ++dt) {
    #pragma unroll
    for (int i = 0; i < 16; ++i) {
      int d = dt * 32 + (i & 3) + 8 * (i >> 2) + 4 * hi;
      Ocomb[(pair * QB + wid * 32 + r) * 67 + d] = oacc[dt][i];
    }
  }
  __syncthreads();

  int q  = tid >> 3;
  int dg = tid & 7;
  float m0 = mlbuf[0][0][q], m1 = mlbuf[1][0][q], m2 = mlbuf[2][0][q], m3 = mlbuf[3][0][q];
  float l0 = mlbuf[0][1][q], l1 = mlbuf[1][1][q], l2 = mlbuf[2][1][q], l3 = mlbuf[3][1][q];
  float ms = fmaxf(fmaxf(m0, m1), fmaxf(m2, m3));
  float w0 = exp2f((m0 - ms) * SC_LOG2E);
  float w1 = exp2f((m1 - ms) * SC_LOG2E);
  float w2 = exp2f((m2 - ms) * SC_LOG2E);
  float w3 = exp2f((m3 - ms) * SC_LOG2E);
  float inv = 1.0f / (l0 * w0 + l1 * w1 + l2 * w2 + l3 * w3);
  float o[8];
  #pragma unroll
  for (int j = 0; j < 8; ++j) {
    o[j] = (Ocomb[(0 * QB + q) * 67 + dg * 8 + j] * w0 +
            Ocomb[(1 * QB + q) * 67 + dg * 8 + j] * w1 +
            Ocomb[(2 * QB + q) * 67 + dg * 8 + j] * w2 +
            Ocomb[(3 * QB + q) * 67 + dg * 8 + j] * w3) * inv;
  }
  float* outp = out + ((size_t)b * S_LEN + q0 + q) * DIM + dg * 8;
  float4 s0; s0.x = o[0]; s0.y = o[1]; s0.z = o[2]; s0.w = o[3];
  float4 s1; s1.x = o[4]; s1.y = o[5]; s1.z = o[6]; s1.w = o[7];
  *reinterpret_cast<float4*>(outp + 0) = s0;
  *reinterpret_cast<float4*>(outp + 4) = s1;
}

extern "C" void kernel_launch(void* const* d_in, const int* in_sizes, int n_in,
                              void* d_out, int out_size, void* d_ws, size_t ws_size,
                              hipStream_t stream) {
  const float* x1 = (const float*)d_in[0];
  const float* x2 = (const float*)d_in[1];
  float* outp = (float*)d_out;
  const size_t need = (size_t)512 * 16384;  // 8 MB image
  if (ws_size >= need) {
    prep_kv<<<dim3(512), dim3(256), 0, stream>>>(x2, (unsigned char*)d_ws);
    attn_fwd<true><<<dim3(512), dim3(512), 0, stream>>>(x1, x2, (const unsigned char*)d_ws, outp);
  } else {
    attn_fwd<false><<<dim3(512), dim3(512), 0, stream>>>(x1, x2, nullptr, outp);
  }
}